// Round 4
// baseline (213.166 us; speedup 1.0000x reference)
//
#include <hip/hip_runtime.h>
#include <math.h>

#define BATCH   2048
#define NROWS   4096   // 2*BATCH
#define LATENT  2048
#define PROJ    256
#define TEMP_INV 2.0f      // 1/0.5
#define BN_EPS  1e-5f
#define COS_EPS 1e-8f

typedef __bf16 bf16x8 __attribute__((ext_vector_type(8)));
typedef float  f32x4  __attribute__((ext_vector_type(4)));

__device__ __forceinline__ unsigned short f2bf(float f) {
    union { float f; unsigned int u; } c; c.f = f;
    return (unsigned short)((c.u + 0x7FFFu + ((c.u >> 16) & 1u)) >> 16);
}
__device__ __forceinline__ float bf2f(unsigned short h) {
    union { unsigned int u; float f; } c; c.u = ((unsigned int)h) << 16;
    return c.f;
}

// async global->LDS, 16 bytes per lane. LDS dest is wave-uniform base + lane*16.
__device__ __forceinline__ void gl_lds16(const unsigned short* g, unsigned short* l) {
    __builtin_amdgcn_global_load_lds(
        (__attribute__((address_space(1))) void*)g,
        (__attribute__((address_space(3))) void*)l, 16, 0, 0);
}

// LDS element offset of (row R, k-chunk lk) under the granule XOR swizzle.
// Granule (R, c) is stored at slot c ^ ((R>>1)&3) within row R's 4 slots.
__device__ __forceinline__ int swz(int R, int lk) {
    return R * 32 + ((lk ^ ((R >> 1) & 3)) << 3);
}

// ---------------------------------------------------------------------------
// Fused fp32->bf16 convert of all four inputs into one contiguous bf16 region
// [Hb(h_i|h_j) | W1b | W2b]. 4 floats/thread.
// ---------------------------------------------------------------------------
#define G1 1048576   // h_i float4-groups
#define G2 2097152
#define G3 3145728
#define G4 3276800
__global__ __launch_bounds__(256) void cvt_all_kernel(
    const float* __restrict__ h_i, const float* __restrict__ h_j,
    const float* __restrict__ W1,  const float* __restrict__ W2,
    unsigned short* __restrict__ dst)
{
    int i = blockIdx.x * 256 + threadIdx.x;
    if (i >= G4) return;
    const float* src; int off;
    if (i < G1)      { src = h_i; off = i; }
    else if (i < G2) { src = h_j; off = i - G1; }
    else if (i < G3) { src = W1;  off = i - G2; }
    else             { src = W2;  off = i - G3; }
    float4 v = reinterpret_cast<const float4*>(src)[off];
    ushort4 o;
    o.x = f2bf(v.x); o.y = f2bf(v.y); o.z = f2bf(v.z); o.w = f2bf(v.w);
    reinterpret_cast<ushort4*>(dst)[i] = o;
}

// ---------------------------------------------------------------------------
// Core MFMA K-loop. 256 threads = 4 waves in 2x2. BM=WM*32, BN=WN*32, BK=32.
// Operands row-major [rows][KSTRIDE] bf16 (B^T-input GEMM); iterates KLEN.
// LDS tiles are 16B-granule XOR-swizzled (bank-conflict-free reads).
// ---------------------------------------------------------------------------
template<int KSTRIDE, int KLEN, int WM, int WN>
__device__ __forceinline__ void mfma_loop(
    const unsigned short* __restrict__ Ab,
    const unsigned short* __restrict__ Bb,
    unsigned short* As, unsigned short* Bs,
    f32x4 acc[WM][WN], int tid)
{
    constexpr int BM = WM * 32;
    constexpr int BN = WN * 32;
    const int wid = tid >> 6, lane = tid & 63;
    const int mblk = (wid >> 1) * (WM * 16);
    const int nblk = (wid & 1) * (WN * 16);
    const int lr = lane & 15, lk = lane >> 4;
    for (int k0 = 0; k0 < KLEN; k0 += 32) {
        __syncthreads();
        #pragma unroll
        for (int u = 0; u < BM / 64; ++u) {
            int li = u * 256 + tid;
            int r = li >> 2;
            int c = (li & 3) ^ ((li >> 3) & 3);   // swizzled source chunk
            gl_lds16(Ab + (size_t)r * KSTRIDE + k0 + c * 8, As + li * 8);
        }
        #pragma unroll
        for (int u = 0; u < BN / 64; ++u) {
            int li = u * 256 + tid;
            int r = li >> 2;
            int c = (li & 3) ^ ((li >> 3) & 3);
            gl_lds16(Bb + (size_t)r * KSTRIDE + k0 + c * 8, Bs + li * 8);
        }
        __syncthreads();
        bf16x8 af[WM], bv[WN];
        #pragma unroll
        for (int i = 0; i < WM; ++i)
            af[i] = *reinterpret_cast<const bf16x8*>(As + swz(mblk + i * 16 + lr, lk));
        #pragma unroll
        for (int j = 0; j < WN; ++j)
            bv[j] = *reinterpret_cast<const bf16x8*>(Bs + swz(nblk + j * 16 + lr, lk));
        #pragma unroll
        for (int i = 0; i < WM; ++i)
            #pragma unroll
            for (int j = 0; j < WN; ++j)
                acc[i][j] = __builtin_amdgcn_mfma_f32_16x16x32_bf16(af[i], bv[j], acc[i][j], 0, 0, 0);
    }
}

// ---------------------------------------------------------------------------
// GEMM1: X[m][n] = sum_k H[m][k]*W1[n][k]  (M=4096, N=2048, K=2048)
// BM=64 x BN=128 -> 1024 blocks (4/CU). Epilogue: bf16 X store + fused BN
// column stats (sum, sumsq) from the fp32 accumulators.
// ---------------------------------------------------------------------------
__global__ __launch_bounds__(256) void gemm1_mfma(
    const unsigned short* __restrict__ Hb, const unsigned short* __restrict__ W1b,
    unsigned short* __restrict__ Xb, float* __restrict__ sums, float* __restrict__ sumsqs)
{
    __shared__ __align__(16) unsigned short As[64 * 32];
    __shared__ __align__(16) unsigned short Bs[128 * 32];
    const int tid = threadIdx.x;
    const int m0 = blockIdx.y * 64, n0 = blockIdx.x * 128;
    f32x4 zero = {0.f, 0.f, 0.f, 0.f};
    f32x4 acc[2][4];
    #pragma unroll
    for (int i = 0; i < 2; ++i)
        #pragma unroll
        for (int j = 0; j < 4; ++j) acc[i][j] = zero;
    mfma_loop<LATENT, LATENT, 2, 4>(Hb + (size_t)m0 * LATENT, W1b + (size_t)n0 * LATENT,
                                    As, Bs, acc, tid);
    const int wid = tid >> 6, lane = tid & 63;
    const int mblk = (wid >> 1) * 32, nblk = (wid & 1) * 64;
    const int lr = lane & 15, lq = lane >> 4;
    const int half = m0 >> 11;   // m0/BATCH
    #pragma unroll
    for (int j = 0; j < 4; ++j) {
        float s = 0.f, q = 0.f;
        #pragma unroll
        for (int i = 0; i < 2; ++i)
            #pragma unroll
            for (int r = 0; r < 4; ++r) {
                float v = acc[i][j][r];
                s += v; q += v * v;
                int row = m0 + mblk + i * 16 + lq * 4 + r;
                int col = n0 + nblk + j * 16 + lr;
                Xb[(size_t)row * LATENT + col] = f2bf(v);
            }
        // reduce over the 32 rows this wave covers (lanes lane^16, lane^32)
        s += __shfl_xor(s, 16, 64);  q += __shfl_xor(q, 16, 64);
        s += __shfl_xor(s, 32, 64);  q += __shfl_xor(q, 32, 64);
        if (lq == 0) {
            int col = n0 + nblk + j * 16 + lr;
            atomicAdd(&sums[half * LATENT + col], s);
            atomicAdd(&sumsqs[half * LATENT + col], q);
        }
    }
}

// ---------------------------------------------------------------------------
// BN scale/shift computed inline from stats + ReLU, in-place on bf16 X.
// One block per row (256 thr x 8 elems = 2048 cols).
// ---------------------------------------------------------------------------
__global__ __launch_bounds__(256) void bnrelu_kernel(
    unsigned short* __restrict__ Xb, const float* __restrict__ sums,
    const float* __restrict__ sumsqs, const float* __restrict__ gamma,
    const float* __restrict__ beta)
{
    const int row = blockIdx.x;
    const int half = row >> 11;
    const int col = threadIdx.x * 8;
    size_t idx = (size_t)row * LATENT + col;
    ushort4 a = *reinterpret_cast<const ushort4*>(Xb + idx);
    ushort4 b = *reinterpret_cast<const ushort4*>(Xb + idx + 4);
    const float* S = sums + half * LATENT + col;
    const float* Q = sumsqs + half * LATENT + col;
    float4 s0 = *reinterpret_cast<const float4*>(S);
    float4 s1 = *reinterpret_cast<const float4*>(S + 4);
    float4 q0 = *reinterpret_cast<const float4*>(Q);
    float4 q1 = *reinterpret_cast<const float4*>(Q + 4);
    float4 g0 = *reinterpret_cast<const float4*>(gamma + col);
    float4 g1 = *reinterpret_cast<const float4*>(gamma + col + 4);
    float4 e0 = *reinterpret_cast<const float4*>(beta + col);
    float4 e1 = *reinterpret_cast<const float4*>(beta + col + 4);
    ushort4 oa, ob;
    #define BN1(x, sv, qv, gv, ev, o) { \
        float mu = (sv) * (1.0f / BATCH); \
        float var = (qv) * (1.0f / BATCH) - mu * mu; \
        float sc = (gv) * rsqrtf(var + BN_EPS); \
        float sh = (ev) - mu * sc; \
        o = f2bf(fmaxf(fmaf(bf2f(x), sc, sh), 0.f)); }
    BN1(a.x, s0.x, q0.x, g0.x, e0.x, oa.x) BN1(a.y, s0.y, q0.y, g0.y, e0.y, oa.y)
    BN1(a.z, s0.z, q0.z, g0.z, e0.z, oa.z) BN1(a.w, s0.w, q0.w, g0.w, e0.w, oa.w)
    BN1(b.x, s1.x, q1.x, g1.x, e1.x, ob.x) BN1(b.y, s1.y, q1.y, g1.y, e1.y, ob.y)
    BN1(b.z, s1.z, q1.z, g1.z, e1.z, ob.z) BN1(b.w, s1.w, q1.w, g1.w, e1.w, ob.w)
    #undef BN1
    *reinterpret_cast<ushort4*>(Xb + idx) = oa;
    *reinterpret_cast<ushort4*>(Xb + idx + 4) = ob;
}

// ---------------------------------------------------------------------------
// GEMM2 split-K=4: Zp[kc][m][n] = sum_{k in chunk} Xb[m][k]*W2[n][k]
// BM=128 x BN=64 x KC=512 -> 512 blocks (2/CU).
// ---------------------------------------------------------------------------
__global__ __launch_bounds__(256) void gemm2_mfma(
    const unsigned short* __restrict__ Xb, const unsigned short* __restrict__ W2b,
    float* __restrict__ Zp)
{
    __shared__ __align__(16) unsigned short As[128 * 32];
    __shared__ __align__(16) unsigned short Bs[64 * 32];
    const int tid = threadIdx.x;
    const int m0 = blockIdx.y * 128, n0 = blockIdx.x * 64, kc = blockIdx.z;
    f32x4 zero = {0.f, 0.f, 0.f, 0.f};
    f32x4 acc[4][2];
    #pragma unroll
    for (int i = 0; i < 4; ++i) { acc[i][0] = zero; acc[i][1] = zero; }
    mfma_loop<LATENT, 512, 4, 2>(Xb + (size_t)m0 * LATENT + kc * 512,
                                 W2b + (size_t)n0 * LATENT + kc * 512, As, Bs, acc, tid);
    float* Zk = Zp + (size_t)kc * NROWS * PROJ;
    const int wid = tid >> 6, lane = tid & 63;
    const int mblk = (wid >> 1) * 64, nblk = (wid & 1) * 32;
    const int lr = lane & 15, lq = lane >> 4;
    #pragma unroll
    for (int i = 0; i < 4; ++i)
        #pragma unroll
        for (int j = 0; j < 2; ++j)
            #pragma unroll
            for (int r = 0; r < 4; ++r) {
                int row = m0 + mblk + i * 16 + lq * 4 + r;
                int col = n0 + nblk + j * 16 + lr;
                Zk[(size_t)row * PROJ + col] = acc[i][j][r];
            }
}

// ---------------------------------------------------------------------------
// Sum 4 K-partials + b2, L2-normalize row -> bf16 ZNb. One wave per row.
// ---------------------------------------------------------------------------
__global__ __launch_bounds__(256) void rownorm_kernel(
    const float* __restrict__ Zp, const float* __restrict__ b2,
    unsigned short* __restrict__ ZNb)
{
    const int wave = threadIdx.x >> 6;
    const int lane = threadIdx.x & 63;
    const int row = blockIdx.x * 4 + wave;
    float v[4];
    float sq = 0.f;
    #pragma unroll
    for (int i = 0; i < 4; ++i) {
        int col = lane + i * 64;
        float t = b2[col];
        #pragma unroll
        for (int c = 0; c < 4; ++c)
            t += Zp[(size_t)c * NROWS * PROJ + (size_t)row * PROJ + col];
        v[i] = t;
        sq += t * t;
    }
    #pragma unroll
    for (int off = 32; off > 0; off >>= 1) sq += __shfl_xor(sq, off, 64);
    float inv = 1.0f / fmaxf(sqrtf(sq), COS_EPS);
    #pragma unroll
    for (int i = 0; i < 4; ++i)
        ZNb[(size_t)row * PROJ + lane + i * 64] = f2bf(v[i] * inv);
}

// ---------------------------------------------------------------------------
// sim tile via MFMA + fused exp/rowsum/diag/pos. K=PROJ=256.
// ---------------------------------------------------------------------------
__global__ __launch_bounds__(256) void simlse_mfma(
    const unsigned short* __restrict__ ZNb, float* __restrict__ rowsum,
    float* __restrict__ dgA, float* __restrict__ posA)
{
    __shared__ __align__(16) unsigned short As[128 * 32];
    __shared__ __align__(16) unsigned short Bs[128 * 32];
    const int tid = threadIdx.x;
    const int r0 = blockIdx.y * 128, j0 = blockIdx.x * 128;
    f32x4 zero = {0.f, 0.f, 0.f, 0.f};
    f32x4 acc[4][4];
    #pragma unroll
    for (int i = 0; i < 4; ++i)
        #pragma unroll
        for (int j = 0; j < 4; ++j) acc[i][j] = zero;
    mfma_loop<PROJ, PROJ, 4, 4>(ZNb + (size_t)r0 * PROJ, ZNb + (size_t)j0 * PROJ,
                                As, Bs, acc, tid);
    const int wid = tid >> 6, lane = tid & 63;
    const int mblk = (wid >> 1) * 64, nblk = (wid & 1) * 64;
    const int lr = lane & 15, lq = lane >> 4;
    #pragma unroll
    for (int i = 0; i < 4; ++i)
        #pragma unroll
        for (int r = 0; r < 4; ++r) {
            int R = r0 + mblk + i * 16 + lq * 4 + r;
            int P = (R < BATCH) ? R + BATCH : R - BATCH;
            float t = 0.f;
            #pragma unroll
            for (int j = 0; j < 4; ++j) {
                int J = j0 + nblk + j * 16 + lr;
                float s = acc[i][j][r] * TEMP_INV;
                float e = __expf(s);
                t += e;
                if (J == R) dgA[R] = e;     // unique writer
                if (J == P) posA[R] = s;    // unique writer
            }
            t += __shfl_xor(t, 1, 64);
            t += __shfl_xor(t, 2, 64);
            t += __shfl_xor(t, 4, 64);
            t += __shfl_xor(t, 8, 64);
            if (lr == 0) atomicAdd(&rowsum[R], t);
        }
}

// loss = (1/N) * sum_r [ log(rowsum_r - diag_r) - pos_r ]
__global__ __launch_bounds__(256) void loss_kernel(
    const float* __restrict__ rowsum, const float* __restrict__ dgA,
    const float* __restrict__ posA, float* __restrict__ out)
{
    __shared__ float red[256];
    float s = 0.f;
    for (int r = threadIdx.x; r < NROWS; r += 256)
        s += logf(rowsum[r] - dgA[r]) - posA[r];
    red[threadIdx.x] = s;
    __syncthreads();
    for (int off = 128; off > 0; off >>= 1) {
        if (threadIdx.x < off) red[threadIdx.x] += red[threadIdx.x + off];
        __syncthreads();
    }
    if (threadIdx.x == 0) out[0] = red[0] * (1.0f / NROWS);
}

// ---------------------------------------------------------------------------
extern "C" void kernel_launch(void* const* d_in, const int* in_sizes, int n_in,
                              void* d_out, int out_size, void* d_ws, size_t ws_size,
                              hipStream_t stream)
{
    const float* h_i   = (const float*)d_in[0];
    const float* h_j   = (const float*)d_in[1];
    const float* W1    = (const float*)d_in[2];
    const float* gamma = (const float*)d_in[3];
    const float* beta  = (const float*)d_in[4];
    const float* W2    = (const float*)d_in[5];
    const float* b2    = (const float*)d_in[6];
    float* out = (float*)d_out;

    // workspace (~62 MB)
    float* Zp     = (float*)d_ws;                        // 4 * 4096*256 fp32
    float* sums   = Zp + (size_t)4 * NROWS * PROJ;       // 4096
    float* sumsqs = sums + 2 * LATENT;                   // 4096
    float* rowsum = sumsqs + 2 * LATENT;                 // 4096
    float* dgA    = rowsum + NROWS;                      // 4096
    float* posA   = dgA + NROWS;                         // 4096
    unsigned short* Hb  = (unsigned short*)(posA + NROWS);   // 4096*2048 bf16
    unsigned short* W1b = Hb + (size_t)NROWS * LATENT;       // 2048*2048
    unsigned short* W2b = W1b + (size_t)LATENT * LATENT;     // 256*2048
    unsigned short* Xb  = W2b + (size_t)PROJ * LATENT;       // 4096*2048
    unsigned short* ZNb = Xb + (size_t)NROWS * LATENT;       // 4096*256

    // zero atomic accumulators (sums, sumsqs, rowsum contiguous = 12288 floats)
    hipMemsetAsync(sums, 0, (size_t)(4 * LATENT + NROWS) * sizeof(float), stream);

    cvt_all_kernel<<<(G4 + 255) / 256, 256, 0, stream>>>(h_i, h_j, W1, W2, Hb);
    gemm1_mfma<<<dim3(LATENT / 128, NROWS / 64), 256, 0, stream>>>(Hb, W1b, Xb, sums, sumsqs);
    bnrelu_kernel<<<NROWS, 256, 0, stream>>>(Xb, sums, sumsqs, gamma, beta);
    gemm2_mfma<<<dim3(PROJ / 64, NROWS / 128, 4), 256, 0, stream>>>(Xb, W2b, Zp);
    rownorm_kernel<<<NROWS / 4, 256, 0, stream>>>(Zp, b2, ZNb);
    simlse_mfma<<<dim3(NROWS / 128, NROWS / 128), 256, 0, stream>>>(ZNb, rowsum, dgA, posA);
    loss_kernel<<<1, 256, 0, stream>>>(rowsum, dgA, posA, out);
}

// Round 5
// 204.732 us; speedup vs baseline: 1.0412x; 1.0412x over previous
//
#include <hip/hip_runtime.h>
#include <math.h>

#define BATCH   2048
#define NROWS   4096   // 2*BATCH
#define LATENT  2048
#define PROJ    256
#define TEMP_INV 2.0f      // 1/0.5
#define BN_EPS  1e-5f
#define COS_EPS 1e-8f

typedef __bf16 bf16x8 __attribute__((ext_vector_type(8)));
typedef float  f32x4  __attribute__((ext_vector_type(4)));

__device__ __forceinline__ unsigned short f2bf(float f) {
    union { float f; unsigned int u; } c; c.f = f;
    return (unsigned short)((c.u + 0x7FFFu + ((c.u >> 16) & 1u)) >> 16);
}
__device__ __forceinline__ float bf2f(unsigned short h) {
    union { unsigned int u; float f; } c; c.u = ((unsigned int)h) << 16;
    return c.f;
}

// async global->LDS, 16 bytes per lane. LDS dest is wave-uniform base + lane*16.
__device__ __forceinline__ void gl_lds16(const unsigned short* g, unsigned short* l) {
    __builtin_amdgcn_global_load_lds(
        (__attribute__((address_space(1))) void*)g,
        (__attribute__((address_space(3))) void*)l, 16, 0, 0);
}

// LDS element offset of (row R, k-chunk lk) under the granule XOR swizzle.
// Granule (R, c) is stored at slot c ^ ((R>>1)&3) within row R's 4 slots.
__device__ __forceinline__ int swz(int R, int lk) {
    return R * 32 + ((lk ^ ((R >> 1) & 3)) << 3);
}

// ---------------------------------------------------------------------------
// Fused fp32->bf16 convert of all four inputs into one contiguous bf16 region
// [Hb(h_i|h_j) | W1b | W2b]. 4 floats/thread.
// ---------------------------------------------------------------------------
#define G1 1048576   // h_i float4-groups
#define G2 2097152
#define G3 3145728
#define G4 3276800
__global__ __launch_bounds__(256) void cvt_all_kernel(
    const float* __restrict__ h_i, const float* __restrict__ h_j,
    const float* __restrict__ W1,  const float* __restrict__ W2,
    unsigned short* __restrict__ dst)
{
    int i = blockIdx.x * 256 + threadIdx.x;
    if (i >= G4) return;
    const float* src; int off;
    if (i < G1)      { src = h_i; off = i; }
    else if (i < G2) { src = h_j; off = i - G1; }
    else if (i < G3) { src = W1;  off = i - G2; }
    else             { src = W2;  off = i - G3; }
    float4 v = reinterpret_cast<const float4*>(src)[off];
    ushort4 o;
    o.x = f2bf(v.x); o.y = f2bf(v.y); o.z = f2bf(v.z); o.w = f2bf(v.w);
    reinterpret_cast<ushort4*>(dst)[i] = o;
}

// ---------------------------------------------------------------------------
// Core MFMA K-loop. 256 threads = 4 waves in 2x2. BM=WM*32, BN=WN*32, BK=32.
// Operands row-major [rows][KSTRIDE] bf16 (B^T-input GEMM); iterates KLEN.
// LDS tiles are 16B-granule XOR-swizzled (bank-conflict-free reads).
// ---------------------------------------------------------------------------
template<int KSTRIDE, int KLEN, int WM, int WN>
__device__ __forceinline__ void mfma_loop(
    const unsigned short* __restrict__ Ab,
    const unsigned short* __restrict__ Bb,
    unsigned short* As, unsigned short* Bs,
    f32x4 acc[WM][WN], int tid)
{
    constexpr int BM = WM * 32;
    constexpr int BN = WN * 32;
    const int wid = tid >> 6, lane = tid & 63;
    const int mblk = (wid >> 1) * (WM * 16);
    const int nblk = (wid & 1) * (WN * 16);
    const int lr = lane & 15, lk = lane >> 4;
    for (int k0 = 0; k0 < KLEN; k0 += 32) {
        __syncthreads();
        #pragma unroll
        for (int u = 0; u < BM / 64; ++u) {
            int li = u * 256 + tid;
            int r = li >> 2;
            int c = (li & 3) ^ ((li >> 3) & 3);   // swizzled source chunk
            gl_lds16(Ab + (size_t)r * KSTRIDE + k0 + c * 8, As + li * 8);
        }
        #pragma unroll
        for (int u = 0; u < BN / 64; ++u) {
            int li = u * 256 + tid;
            int r = li >> 2;
            int c = (li & 3) ^ ((li >> 3) & 3);
            gl_lds16(Bb + (size_t)r * KSTRIDE + k0 + c * 8, Bs + li * 8);
        }
        __syncthreads();
        bf16x8 af[WM], bv[WN];
        #pragma unroll
        for (int i = 0; i < WM; ++i)
            af[i] = *reinterpret_cast<const bf16x8*>(As + swz(mblk + i * 16 + lr, lk));
        #pragma unroll
        for (int j = 0; j < WN; ++j)
            bv[j] = *reinterpret_cast<const bf16x8*>(Bs + swz(nblk + j * 16 + lr, lk));
        #pragma unroll
        for (int i = 0; i < WM; ++i)
            #pragma unroll
            for (int j = 0; j < WN; ++j)
                acc[i][j] = __builtin_amdgcn_mfma_f32_16x16x32_bf16(af[i], bv[j], acc[i][j], 0, 0, 0);
    }
}

// ---------------------------------------------------------------------------
// GEMM1: X[m][n] = sum_k H[m][k]*W1[n][k]  (M=4096, N=2048, K=2048)
// BM=128 x BN=128 -> 512 blocks. WM=WN=4 (21.8 FLOP/LDS-byte). Epilogue:
// bf16 X store + fused BN column stats (sum, sumsq) from fp32 accumulators.
// ---------------------------------------------------------------------------
__global__ __launch_bounds__(256) void gemm1_mfma(
    const unsigned short* __restrict__ Hb, const unsigned short* __restrict__ W1b,
    unsigned short* __restrict__ Xb, float* __restrict__ sums, float* __restrict__ sumsqs)
{
    __shared__ __align__(16) unsigned short As[128 * 32];
    __shared__ __align__(16) unsigned short Bs[128 * 32];
    const int tid = threadIdx.x;
    const int m0 = blockIdx.y * 128, n0 = blockIdx.x * 128;
    f32x4 zero = {0.f, 0.f, 0.f, 0.f};
    f32x4 acc[4][4];
    #pragma unroll
    for (int i = 0; i < 4; ++i)
        #pragma unroll
        for (int j = 0; j < 4; ++j) acc[i][j] = zero;
    mfma_loop<LATENT, LATENT, 4, 4>(Hb + (size_t)m0 * LATENT, W1b + (size_t)n0 * LATENT,
                                    As, Bs, acc, tid);
    const int wid = tid >> 6, lane = tid & 63;
    const int mblk = (wid >> 1) * 64, nblk = (wid & 1) * 64;
    const int lr = lane & 15, lq = lane >> 4;
    const int half = m0 >> 11;   // m0/BATCH (tile is entirely in one half)
    #pragma unroll
    for (int j = 0; j < 4; ++j) {
        float s = 0.f, q = 0.f;
        #pragma unroll
        for (int i = 0; i < 4; ++i)
            #pragma unroll
            for (int r = 0; r < 4; ++r) {
                float v = acc[i][j][r];
                s += v; q += v * v;
                int row = m0 + mblk + i * 16 + lq * 4 + r;
                int col = n0 + nblk + j * 16 + lr;
                Xb[(size_t)row * LATENT + col] = f2bf(v);
            }
        // reduce over lq (lanes ^16, ^32): covers this wave's 64 rows
        s += __shfl_xor(s, 16, 64);  q += __shfl_xor(q, 16, 64);
        s += __shfl_xor(s, 32, 64);  q += __shfl_xor(q, 32, 64);
        if (lq == 0) {
            int col = n0 + nblk + j * 16 + lr;
            atomicAdd(&sums[half * LATENT + col], s);
            atomicAdd(&sumsqs[half * LATENT + col], q);
        }
    }
}

// ---------------------------------------------------------------------------
// BN scale/shift computed inline from stats + ReLU, in-place on bf16 X.
// One block per row (256 thr x 8 elems = 2048 cols).
// ---------------------------------------------------------------------------
__global__ __launch_bounds__(256) void bnrelu_kernel(
    unsigned short* __restrict__ Xb, const float* __restrict__ sums,
    const float* __restrict__ sumsqs, const float* __restrict__ gamma,
    const float* __restrict__ beta)
{
    const int row = blockIdx.x;
    const int half = row >> 11;
    const int col = threadIdx.x * 8;
    size_t idx = (size_t)row * LATENT + col;
    ushort4 a = *reinterpret_cast<const ushort4*>(Xb + idx);
    ushort4 b = *reinterpret_cast<const ushort4*>(Xb + idx + 4);
    const float* S = sums + half * LATENT + col;
    const float* Q = sumsqs + half * LATENT + col;
    float4 s0 = *reinterpret_cast<const float4*>(S);
    float4 s1 = *reinterpret_cast<const float4*>(S + 4);
    float4 q0 = *reinterpret_cast<const float4*>(Q);
    float4 q1 = *reinterpret_cast<const float4*>(Q + 4);
    float4 g0 = *reinterpret_cast<const float4*>(gamma + col);
    float4 g1 = *reinterpret_cast<const float4*>(gamma + col + 4);
    float4 e0 = *reinterpret_cast<const float4*>(beta + col);
    float4 e1 = *reinterpret_cast<const float4*>(beta + col + 4);
    ushort4 oa, ob;
    #define BN1(x, sv, qv, gv, ev, o) { \
        float mu = (sv) * (1.0f / BATCH); \
        float var = (qv) * (1.0f / BATCH) - mu * mu; \
        float sc = (gv) * rsqrtf(var + BN_EPS); \
        float sh = (ev) - mu * sc; \
        o = f2bf(fmaxf(fmaf(bf2f(x), sc, sh), 0.f)); }
    BN1(a.x, s0.x, q0.x, g0.x, e0.x, oa.x) BN1(a.y, s0.y, q0.y, g0.y, e0.y, oa.y)
    BN1(a.z, s0.z, q0.z, g0.z, e0.z, oa.z) BN1(a.w, s0.w, q0.w, g0.w, e0.w, oa.w)
    BN1(b.x, s1.x, q1.x, g1.x, e1.x, ob.x) BN1(b.y, s1.y, q1.y, g1.y, e1.y, ob.y)
    BN1(b.z, s1.z, q1.z, g1.z, e1.z, ob.z) BN1(b.w, s1.w, q1.w, g1.w, e1.w, ob.w)
    #undef BN1
    *reinterpret_cast<ushort4*>(Xb + idx) = oa;
    *reinterpret_cast<ushort4*>(Xb + idx + 4) = ob;
}

// ---------------------------------------------------------------------------
// GEMM2 split-K=4: Zp[kc][m][n] = sum_{k in chunk} Xb[m][k]*W2[n][k]
// BM=128 x BN=64 x KC=512 -> 512 blocks (2/CU).
// ---------------------------------------------------------------------------
__global__ __launch_bounds__(256) void gemm2_mfma(
    const unsigned short* __restrict__ Xb, const unsigned short* __restrict__ W2b,
    float* __restrict__ Zp)
{
    __shared__ __align__(16) unsigned short As[128 * 32];
    __shared__ __align__(16) unsigned short Bs[64 * 32];
    const int tid = threadIdx.x;
    const int m0 = blockIdx.y * 128, n0 = blockIdx.x * 64, kc = blockIdx.z;
    f32x4 zero = {0.f, 0.f, 0.f, 0.f};
    f32x4 acc[4][2];
    #pragma unroll
    for (int i = 0; i < 4; ++i) { acc[i][0] = zero; acc[i][1] = zero; }
    mfma_loop<LATENT, 512, 4, 2>(Xb + (size_t)m0 * LATENT + kc * 512,
                                 W2b + (size_t)n0 * LATENT + kc * 512, As, Bs, acc, tid);
    float* Zk = Zp + (size_t)kc * NROWS * PROJ;
    const int wid = tid >> 6, lane = tid & 63;
    const int mblk = (wid >> 1) * 64, nblk = (wid & 1) * 32;
    const int lr = lane & 15, lq = lane >> 4;
    #pragma unroll
    for (int i = 0; i < 4; ++i)
        #pragma unroll
        for (int j = 0; j < 2; ++j)
            #pragma unroll
            for (int r = 0; r < 4; ++r) {
                int row = m0 + mblk + i * 16 + lq * 4 + r;
                int col = n0 + nblk + j * 16 + lr;
                Zk[(size_t)row * PROJ + col] = acc[i][j][r];
            }
}

// ---------------------------------------------------------------------------
// Sum 4 K-partials + b2, L2-normalize row -> bf16 ZNb. One wave per row.
// ---------------------------------------------------------------------------
__global__ __launch_bounds__(256) void rownorm_kernel(
    const float* __restrict__ Zp, const float* __restrict__ b2,
    unsigned short* __restrict__ ZNb)
{
    const int wave = threadIdx.x >> 6;
    const int lane = threadIdx.x & 63;
    const int row = blockIdx.x * 4 + wave;
    float v[4];
    float sq = 0.f;
    #pragma unroll
    for (int i = 0; i < 4; ++i) {
        int col = lane + i * 64;
        float t = b2[col];
        #pragma unroll
        for (int c = 0; c < 4; ++c)
            t += Zp[(size_t)c * NROWS * PROJ + (size_t)row * PROJ + col];
        v[i] = t;
        sq += t * t;
    }
    #pragma unroll
    for (int off = 32; off > 0; off >>= 1) sq += __shfl_xor(sq, off, 64);
    float inv = 1.0f / fmaxf(sqrtf(sq), COS_EPS);
    #pragma unroll
    for (int i = 0; i < 4; ++i)
        ZNb[(size_t)row * PROJ + lane + i * 64] = f2bf(v[i] * inv);
}

// ---------------------------------------------------------------------------
// sim tile via MFMA + fused exp/rowsum/diag/pos. K=PROJ=256.
// ---------------------------------------------------------------------------
__global__ __launch_bounds__(256) void simlse_mfma(
    const unsigned short* __restrict__ ZNb, float* __restrict__ rowsum,
    float* __restrict__ dgA, float* __restrict__ posA)
{
    __shared__ __align__(16) unsigned short As[128 * 32];
    __shared__ __align__(16) unsigned short Bs[128 * 32];
    const int tid = threadIdx.x;
    const int r0 = blockIdx.y * 128, j0 = blockIdx.x * 128;
    f32x4 zero = {0.f, 0.f, 0.f, 0.f};
    f32x4 acc[4][4];
    #pragma unroll
    for (int i = 0; i < 4; ++i)
        #pragma unroll
        for (int j = 0; j < 4; ++j) acc[i][j] = zero;
    mfma_loop<PROJ, PROJ, 4, 4>(ZNb + (size_t)r0 * PROJ, ZNb + (size_t)j0 * PROJ,
                                As, Bs, acc, tid);
    const int wid = tid >> 6, lane = tid & 63;
    const int mblk = (wid >> 1) * 64, nblk = (wid & 1) * 64;
    const int lr = lane & 15, lq = lane >> 4;
    #pragma unroll
    for (int i = 0; i < 4; ++i)
        #pragma unroll
        for (int r = 0; r < 4; ++r) {
            int R = r0 + mblk + i * 16 + lq * 4 + r;
            int P = (R < BATCH) ? R + BATCH : R - BATCH;
            float t = 0.f;
            #pragma unroll
            for (int j = 0; j < 4; ++j) {
                int J = j0 + nblk + j * 16 + lr;
                float s = acc[i][j][r] * TEMP_INV;
                float e = __expf(s);
                t += e;
                if (J == R) dgA[R] = e;     // unique writer
                if (J == P) posA[R] = s;    // unique writer
            }
            t += __shfl_xor(t, 1, 64);
            t += __shfl_xor(t, 2, 64);
            t += __shfl_xor(t, 4, 64);
            t += __shfl_xor(t, 8, 64);
            if (lr == 0) atomicAdd(&rowsum[R], t);
        }
}

// loss = (1/N) * sum_r [ log(rowsum_r - diag_r) - pos_r ]
__global__ __launch_bounds__(256) void loss_kernel(
    const float* __restrict__ rowsum, const float* __restrict__ dgA,
    const float* __restrict__ posA, float* __restrict__ out)
{
    __shared__ float red[256];
    float s = 0.f;
    for (int r = threadIdx.x; r < NROWS; r += 256)
        s += logf(rowsum[r] - dgA[r]) - posA[r];
    red[threadIdx.x] = s;
    __syncthreads();
    for (int off = 128; off > 0; off >>= 1) {
        if (threadIdx.x < off) red[threadIdx.x] += red[threadIdx.x + off];
        __syncthreads();
    }
    if (threadIdx.x == 0) out[0] = red[0] * (1.0f / NROWS);
}

// ---------------------------------------------------------------------------
extern "C" void kernel_launch(void* const* d_in, const int* in_sizes, int n_in,
                              void* d_out, int out_size, void* d_ws, size_t ws_size,
                              hipStream_t stream)
{
    const float* h_i   = (const float*)d_in[0];
    const float* h_j   = (const float*)d_in[1];
    const float* W1    = (const float*)d_in[2];
    const float* gamma = (const float*)d_in[3];
    const float* beta  = (const float*)d_in[4];
    const float* W2    = (const float*)d_in[5];
    const float* b2    = (const float*)d_in[6];
    float* out = (float*)d_out;

    // workspace (~62 MB)
    float* Zp     = (float*)d_ws;                        // 4 * 4096*256 fp32
    float* sums   = Zp + (size_t)4 * NROWS * PROJ;       // 4096
    float* sumsqs = sums + 2 * LATENT;                   // 4096
    float* rowsum = sumsqs + 2 * LATENT;                 // 4096
    float* dgA    = rowsum + NROWS;                      // 4096
    float* posA   = dgA + NROWS;                         // 4096
    unsigned short* Hb  = (unsigned short*)(posA + NROWS);   // 4096*2048 bf16
    unsigned short* W1b = Hb + (size_t)NROWS * LATENT;       // 2048*2048
    unsigned short* W2b = W1b + (size_t)LATENT * LATENT;     // 256*2048
    unsigned short* Xb  = W2b + (size_t)PROJ * LATENT;       // 4096*2048
    unsigned short* ZNb = Xb + (size_t)NROWS * LATENT;       // 4096*256

    // zero atomic accumulators (sums, sumsqs, rowsum contiguous = 12288 floats)
    hipMemsetAsync(sums, 0, (size_t)(4 * LATENT + NROWS) * sizeof(float), stream);

    cvt_all_kernel<<<(G4 + 255) / 256, 256, 0, stream>>>(h_i, h_j, W1, W2, Hb);
    gemm1_mfma<<<dim3(LATENT / 128, NROWS / 128), 256, 0, stream>>>(Hb, W1b, Xb, sums, sumsqs);
    bnrelu_kernel<<<NROWS, 256, 0, stream>>>(Xb, sums, sumsqs, gamma, beta);
    gemm2_mfma<<<dim3(PROJ / 64, NROWS / 128, 4), 256, 0, stream>>>(Xb, W2b, Zp);
    rownorm_kernel<<<NROWS / 4, 256, 0, stream>>>(Zp, b2, ZNb);
    simlse_mfma<<<dim3(NROWS / 128, NROWS / 128), 256, 0, stream>>>(ZNb, rowsum, dgA, posA);
    loss_kernel<<<1, 256, 0, stream>>>(rowsum, dgA, posA, out);
}